// Round 1
// baseline (600.385 us; speedup 1.0000x reference)
//
#include <hip/hip_runtime.h>
#include <hip/hip_bf16.h>

// GCN_55602646614506 — round 1: full pipeline, MFMA bf16 GEMMs, algebraic u1 factorization.
// Journal: u1 einsum factorized via H1/N1 (68.7GF -> 1.1GF); u2 hoisted out of the loop;
// out-einsum fused with adj reduction (never materializes 67MB 'out').

typedef __attribute__((ext_vector_type(4))) float  f32x4;
typedef __attribute__((ext_vector_type(8))) __bf16 bf16x8;
typedef __attribute__((ext_vector_type(4))) __bf16 bf16x4;
typedef __attribute__((ext_vector_type(4))) int    int4v;

#define FEPS 1e-10f
#define LNEPS 1e-5f
#define GAMA_F 0.9f

// ---------------- weight prep ----------------
__global__ void prep_att(const float* __restrict__ w1, const float* __restrict__ w2,
                         const float* __restrict__ w3, const float* __restrict__ b3,
                         __bf16* __restrict__ W1at, __bf16* __restrict__ W1bt,
                         __bf16* __restrict__ W2t, __bf16* __restrict__ W3t,
                         float* __restrict__ b3s) {
  int gid = blockIdx.x * 256 + threadIdx.x;       // 0..1048575
  int d = gid & 1023, ck = gid >> 10;
  int c = ck >> 6, k = ck & 63;
  // W1at[ck][d] = att_w1[c, d, k];  W1bt[ck][d] = att_w1[c, 1024+d, k]
  W1at[(size_t)ck * 1024 + d] = (__bf16)w1[(size_t)c * 131072 + (size_t)d * 64 + k];
  W1bt[(size_t)ck * 1024 + d] = (__bf16)w1[(size_t)c * 131072 + (size_t)(d + 1024) * 64 + k];
  // W2t[ck][s] = att_w2[c, s, k]
  W2t[(size_t)ck * 1024 + d] = (__bf16)w2[(size_t)c * 65536 + (size_t)d * 64 + k];
  // W3t[o][ck2] = att_w3[c2, k2, o]   (o = gid>>10, ck2 = gid&1023 for coalesced writes)
  int o = ck, ck2 = d;
  int c2 = ck2 >> 6, k2 = ck2 & 63;
  W3t[(size_t)o * 1024 + ck2] = (__bf16)w3[(size_t)c2 * 65536 + (size_t)k2 * 1024 + o];
  if (gid < 1024) {
    float s = 0.f;
    for (int cc = 0; cc < 16; ++cc) s += b3[cc * 1024 + gid];
    b3s[gid] = s;
  }
}

__global__ void prep_sp(const float* __restrict__ w1, const float* __restrict__ w2,
                        const float* __restrict__ w3,
                        __bf16* __restrict__ W1t, __bf16* __restrict__ W2t,
                        __bf16* __restrict__ W3t) {
  int gid = blockIdx.x * 256 + threadIdx.x;       // 0..262143
  if (gid < 128 * 64) {                           // SpW1t[n][k], K padded 36->64
    int n = gid >> 6, k = gid & 63;
    W1t[gid] = (k < 36) ? (__bf16)w1[k * 128 + n] : (__bf16)0.f;
  }
  if (gid < 256 * 128) {                          // SpW2t[n][k]
    int n = gid >> 7, k = gid & 127;
    W2t[gid] = (__bf16)w2[k * 256 + n];
  }
  {                                               // SpW3t[n][k], gid covers exactly 1024*256
    int n = gid >> 8, k = gid & 255;
    W3t[gid] = (__bf16)w3[k * 1024 + n];
  }
}

__global__ void init_nodes(const float* __restrict__ node_in, float* __restrict__ node_f,
                           __bf16* __restrict__ node_b, float* __restrict__ hn_f,
                           __bf16* __restrict__ hn_b) {
  int gid = blockIdx.x * 256 + threadIdx.x;       // 0..524287
  float v = node_in[gid];
  node_f[gid] = v;
  node_b[gid] = (__bf16)v;
  if (gid < 32 * 1024) { hn_f[gid] = v; hn_b[gid] = (__bf16)v; }
}

// ---------------- spatial features ----------------
__device__ __forceinline__ float read_dim(const void* p) {
  int iv = *(const int*)p;                        // hedge: int scalar vs float bit pattern
  if (iv > 0 && iv < (1 << 20)) return (float)iv;
  return *(const float*)p;
}

__global__ void spatial_k(const float* __restrict__ coords, const void* __restrict__ imh,
                          const void* __restrict__ imw, __bf16* __restrict__ f36) {
  int p = blockIdx.x * 256 + threadIdx.x;         // 0..16383
  int i = p >> 9, j = p & 511;
  float H = read_dim(imh), W = read_dim(imw);
  f32x4 b1 = ((const f32x4*)coords)[i];
  f32x4 b2 = ((const f32x4*)coords)[j];
  float c1x = (b1[0] + b1[2]) * 0.5f, c1y = (b1[1] + b1[3]) * 0.5f;
  float c2x = (b2[0] + b2[2]) * 0.5f, c2y = (b2[1] + b2[3]) * 0.5f;
  float b1w = b1[2] - b1[0], b1h = b1[3] - b1[1];
  float b2w = b2[2] - b2[0], b2h = b2[3] - b2[1];
  float dx = fabsf(c2x - c1x) / (b1w + FEPS);
  float dy = fabsf(c2y - c1y) / (b1h + FEPS);
  float ltx = fmaxf(b1[0], b2[0]), lty = fmaxf(b1[1], b2[1]);
  float rbx = fminf(b1[2], b2[2]), rby = fminf(b1[3], b2[3]);
  float inter = fmaxf(rbx - ltx, 0.f) * fmaxf(rby - lty, 0.f);
  float a1 = b1w * b1h, a2 = b2w * b2h;
  float iou = inter / (a1 + a2 - inter);
  float f[18];
  f[0] = c1x / W;  f[1] = c1y / H;  f[2] = c2x / W;  f[3] = c2y / H;
  f[4] = b1w / W;  f[5] = b1h / H;  f[6] = b2w / W;  f[7] = b2h / H;
  f[8] = a1 / (H * W); f[9] = a2 / (H * W); f[10] = a2 / (a1 + FEPS);
  f[11] = b1w / (b1h + FEPS); f[12] = b2w / (b2h + FEPS); f[13] = iou;
  f[14] = (c2x > c1x) ? dx : 0.f; f[15] = (c2x < c1x) ? dx : 0.f;
  f[16] = (c2y > c1y) ? dy : 0.f; f[17] = (c2y < c1y) ? dy : 0.f;
  __bf16 o[64];
  #pragma unroll
  for (int q = 0; q < 18; ++q) { o[q] = (__bf16)f[q]; o[18 + q] = (__bf16)logf(f[q] + FEPS); }
  #pragma unroll
  for (int q = 36; q < 64; ++q) o[q] = (__bf16)0.f;
  bf16x8* dst = (bf16x8*)(f36 + (size_t)p * 64);
  #pragma unroll
  for (int q = 0; q < 8; ++q) dst[q] = *(bf16x8*)&o[q * 8];
}

// ---------------- generic MFMA GEMM: C = epi(A[MxK] @ Bt[NxK]^T + bias) ----------------
// EPI: 0 = relu+bias -> bf16; 1 = bias -> bf16; 2 = bias -> f32; 3 = plain -> f32
template <int EPI>
__global__ __launch_bounds__(256)
void gemm_bt(const __bf16* __restrict__ A, const __bf16* __restrict__ Bt,
             const float* __restrict__ bias, void* __restrict__ C,
             int M, int N, int K) {
  __shared__ __align__(16) __bf16 As[128 * 64];
  __shared__ __align__(16) __bf16 Bs[128 * 64];
  const int t = threadIdx.x;
  const int lane = t & 63, wv = t >> 6;
  const int wr = wv >> 1, wc = wv & 1;
  const int lr = lane & 15, lg = lane >> 4;
  const int m0 = blockIdx.x * 128, n0 = blockIdx.y * 128;

  f32x4 acc[4][4] = {};
  const int nkt = K >> 6;
  for (int kt = 0; kt < nkt; ++kt) {
    const int k0 = kt << 6;
    int4v ar[4], br[4];
    #pragma unroll
    for (int it = 0; it < 4; ++it) {
      int chunk = it * 256 + t;
      int row = chunk >> 3;
      int kl = (chunk & 7) << 3;
      int ga = m0 + row; if (ga >= M) ga = M - 1;
      ar[it] = *(const int4v*)(A + (size_t)ga * K + k0 + kl);
      int gb = n0 + row; if (gb >= N) gb = N - 1;
      br[it] = *(const int4v*)(Bt + (size_t)gb * K + k0 + kl);
    }
    __syncthreads();
    #pragma unroll
    for (int it = 0; it < 4; ++it) {
      int chunk = it * 256 + t;
      int row = chunk >> 3;
      int kl = (chunk & 7) << 3;
      int sk = kl ^ ((row & 7) << 3);             // T2 XOR swizzle (both sides)
      *(int4v*)&As[row * 64 + sk] = ar[it];
      *(int4v*)&Bs[row * 64 + sk] = br[it];
    }
    __syncthreads();
    #pragma unroll
    for (int ks = 0; ks < 2; ++ks) {
      bf16x8 af[4], bfr[4];
      #pragma unroll
      for (int mi = 0; mi < 4; ++mi) {
        int row = wr * 64 + mi * 16 + lr;
        int sk = (ks * 32 + lg * 8) ^ ((row & 7) << 3);
        af[mi] = *(const bf16x8*)&As[row * 64 + sk];
      }
      #pragma unroll
      for (int ni = 0; ni < 4; ++ni) {
        int row = wc * 64 + ni * 16 + lr;
        int sk = (ks * 32 + lg * 8) ^ ((row & 7) << 3);
        bfr[ni] = *(const bf16x8*)&Bs[row * 64 + sk];
      }
      #pragma unroll
      for (int mi = 0; mi < 4; ++mi)
        #pragma unroll
        for (int ni = 0; ni < 4; ++ni)
          acc[mi][ni] = __builtin_amdgcn_mfma_f32_16x16x32_bf16(af[mi], bfr[ni], acc[mi][ni], 0, 0, 0);
    }
  }
  // epilogue: D row = 4*lg + r, col = lr within each 16x16 fragment
  #pragma unroll
  for (int mi = 0; mi < 4; ++mi) {
    #pragma unroll
    for (int r = 0; r < 4; ++r) {
      int R = m0 + wr * 64 + mi * 16 + lg * 4 + r;
      if (R >= M) continue;
      #pragma unroll
      for (int ni = 0; ni < 4; ++ni) {
        int Cc = n0 + wc * 64 + ni * 16 + lr;
        float v = acc[mi][ni][r];
        if constexpr (EPI == 0) {
          v = fmaxf(v + bias[Cc], 0.f);
          ((__bf16*)C)[(size_t)R * N + Cc] = (__bf16)v;
        } else if constexpr (EPI == 1) {
          ((__bf16*)C)[(size_t)R * N + Cc] = (__bf16)(v + bias[Cc]);
        } else if constexpr (EPI == 2) {
          ((float*)C)[(size_t)R * N + Cc] = v + bias[Cc];
        } else {
          ((float*)C)[(size_t)R * N + Cc] = v;
        }
      }
    }
  }
}

// ---------------- fused hdn-build + GEMM + adjacency-dot epilogue ----------------
// out[p,o] = sum_ck relu((H1[i,ck]+N1[j,ck]) * u2[p,ck]) * W3t[o,ck]
// adjpre[p] += sum_o relu(out[p,o]+b3s[o]) * adjw[o]   (partial over this block's cols)
__global__ __launch_bounds__(256)
void fused_out(const __bf16* __restrict__ U2, const float* __restrict__ H1,
               const float* __restrict__ N1, const __bf16* __restrict__ W3t,
               const float* __restrict__ b3s, const float* __restrict__ adjw,
               float* __restrict__ adjpre) {
  __shared__ __align__(16) __bf16 As[128 * 64];
  __shared__ __align__(16) __bf16 Bs[128 * 64];
  const int t = threadIdx.x;
  const int lane = t & 63, wv = t >> 6;
  const int wr = wv >> 1, wc = wv & 1;
  const int lr = lane & 15, lg = lane >> 4;
  const int m0 = blockIdx.x * 128, n0 = blockIdx.y * 128;
  const int i_h = m0 >> 9;                        // constant per tile (128 | 512)
  const int j0 = m0 & 511;

  f32x4 acc[4][4] = {};
  for (int kt = 0; kt < 16; ++kt) {
    const int k0 = kt << 6;
    int4v ar[4], br[4];
    #pragma unroll
    for (int it = 0; it < 4; ++it) {
      int chunk = it * 256 + t;
      int row = chunk >> 3;
      int kl = (chunk & 7) << 3;
      bf16x8 u2v = *(const bf16x8*)(U2 + (size_t)(m0 + row) * 1024 + k0 + kl);
      const float* n1p = N1 + (size_t)(j0 + row) * 1024 + k0 + kl;
      const float* h1p = H1 + (size_t)i_h * 1024 + k0 + kl;
      bf16x8 hv;
      #pragma unroll
      for (int e = 0; e < 8; ++e) {
        float pr = (h1p[e] + n1p[e]) * (float)u2v[e];
        hv[e] = (__bf16)fmaxf(pr, 0.f);
      }
      ar[it] = __builtin_bit_cast(int4v, hv);
      int gb = n0 + row;
      br[it] = *(const int4v*)(W3t + (size_t)gb * 1024 + k0 + kl);
    }
    __syncthreads();
    #pragma unroll
    for (int it = 0; it < 4; ++it) {
      int chunk = it * 256 + t;
      int row = chunk >> 3;
      int kl = (chunk & 7) << 3;
      int sk = kl ^ ((row & 7) << 3);
      *(int4v*)&As[row * 64 + sk] = ar[it];
      *(int4v*)&Bs[row * 64 + sk] = br[it];
    }
    __syncthreads();
    #pragma unroll
    for (int ks = 0; ks < 2; ++ks) {
      bf16x8 af[4], bfr[4];
      #pragma unroll
      for (int mi = 0; mi < 4; ++mi) {
        int row = wr * 64 + mi * 16 + lr;
        int sk = (ks * 32 + lg * 8) ^ ((row & 7) << 3);
        af[mi] = *(const bf16x8*)&As[row * 64 + sk];
      }
      #pragma unroll
      for (int ni = 0; ni < 4; ++ni) {
        int row = wc * 64 + ni * 16 + lr;
        int sk = (ks * 32 + lg * 8) ^ ((row & 7) << 3);
        bfr[ni] = *(const bf16x8*)&Bs[row * 64 + sk];
      }
      #pragma unroll
      for (int mi = 0; mi < 4; ++mi)
        #pragma unroll
        for (int ni = 0; ni < 4; ++ni)
          acc[mi][ni] = __builtin_amdgcn_mfma_f32_16x16x32_bf16(af[mi], bfr[ni], acc[mi][ni], 0, 0, 0);
    }
  }
  // adjacency partial epilogue
  float b3v[4], awv[4];
  #pragma unroll
  for (int ni = 0; ni < 4; ++ni) {
    int Cc = n0 + wc * 64 + ni * 16 + lr;
    b3v[ni] = b3s[Cc];
    awv[ni] = adjw[Cc];
  }
  #pragma unroll
  for (int mi = 0; mi < 4; ++mi) {
    #pragma unroll
    for (int r = 0; r < 4; ++r) {
      float s = 0.f;
      #pragma unroll
      for (int ni = 0; ni < 4; ++ni)
        s += fmaxf(acc[mi][ni][r] + b3v[ni], 0.f) * awv[ni];
      s += __shfl_xor(s, 1);
      s += __shfl_xor(s, 2);
      s += __shfl_xor(s, 4);
      s += __shfl_xor(s, 8);
      if (lr == 0)
        atomicAdd(&adjpre[m0 + wr * 64 + mi * 16 + lg * 4 + r], s);
    }
  }
}

// ---------------- adjacency finalize / messages / LN / gather ----------------
__global__ void adj_fin(const float* __restrict__ pre, const float* __restrict__ adjb,
                        float* __restrict__ adj) {
  int p = blockIdx.x * 256 + threadIdx.x;
  adj[p] = fmaxf(pre[p] + adjb[0], 0.f);
}

__global__ void hn_msg_k(const float* __restrict__ adj, const float* __restrict__ node,
                         float* __restrict__ msg) {
  int i = blockIdx.x, t = threadIdx.x;
  const f32x4* n4 = (const f32x4*)node;
  f32x4 acc = {0.f, 0.f, 0.f, 0.f};
  for (int j = 0; j < 512; ++j) {
    float a = adj[i * 512 + j];
    acc += a * n4[j * 256 + t];
  }
  ((f32x4*)msg)[i * 256 + t] = acc;
}

__global__ void nd_msg_k(const float* __restrict__ adj, const float* __restrict__ hn,
                         float* __restrict__ msg) {
  int j = blockIdx.x, t = threadIdx.x;
  const f32x4* h4 = (const f32x4*)hn;
  f32x4 acc = {0.f, 0.f, 0.f, 0.f};
  for (int i = 0; i < 32; ++i) {
    float a = adj[i * 512 + j];
    acc += a * h4[i * 256 + t];
  }
  ((f32x4*)msg)[j * 256 + t] = acc;
}

__global__ void ln_k(float* __restrict__ X, const float* __restrict__ msg,
                     const float* __restrict__ g, const float* __restrict__ b,
                     __bf16* __restrict__ Xbf) {
  __shared__ float sbuf[4];
  int row = blockIdx.x, t = threadIdx.x;
  f32x4 x = ((const f32x4*)X)[row * 256 + t];
  f32x4 m = ((const f32x4*)msg)[row * 256 + t];
  f32x4 y;
  #pragma unroll
  for (int e = 0; e < 4; ++e) y[e] = x[e] * GAMA_F + (1.0f - GAMA_F) * m[e];
  float s = y[0] + y[1] + y[2] + y[3];
  #pragma unroll
  for (int mm = 32; mm >= 1; mm >>= 1) s += __shfl_xor(s, mm);
  if ((t & 63) == 0) sbuf[t >> 6] = s;
  __syncthreads();
  float mean = (sbuf[0] + sbuf[1] + sbuf[2] + sbuf[3]) * (1.0f / 1024.0f);
  __syncthreads();
  f32x4 d;
  #pragma unroll
  for (int e = 0; e < 4; ++e) d[e] = y[e] - mean;
  float sq = d[0] * d[0] + d[1] * d[1] + d[2] * d[2] + d[3] * d[3];
  #pragma unroll
  for (int mm = 32; mm >= 1; mm >>= 1) sq += __shfl_xor(sq, mm);
  if ((t & 63) == 0) sbuf[t >> 6] = sq;
  __syncthreads();
  float var = (sbuf[0] + sbuf[1] + sbuf[2] + sbuf[3]) * (1.0f / 1024.0f);
  float inv = rsqrtf(var + LNEPS);
  f32x4 gg = ((const f32x4*)g)[t];
  f32x4 bb = ((const f32x4*)b)[t];
  f32x4 o;
  bf16x4 ob;
  #pragma unroll
  for (int e = 0; e < 4; ++e) { o[e] = d[e] * inv * gg[e] + bb[e]; ob[e] = (__bf16)o[e]; }
  ((f32x4*)X)[row * 256 + t] = o;
  *(bf16x4*)(Xbf + (size_t)row * 1024 + t * 4) = ob;
}

__global__ void gather_k(const float* __restrict__ hn, const float* __restrict__ node,
                         const float* __restrict__ adj, float* __restrict__ out) {
  int p = blockIdx.x, t = threadIdx.x;
  int i = p >> 9, j = p & 511;
  if (i == j) return;
  int m = p - (p + 512) / 513;                    // skip diagonal pairs (p = 513*i)
  float* out0 = out;
  float* out1 = out + (size_t)16352 * 1024;
  float* out2 = out1 + (size_t)16352 * 1024;
  ((f32x4*)out0)[(size_t)m * 256 + t] = ((const f32x4*)hn)[i * 256 + t];
  ((f32x4*)out1)[(size_t)m * 256 + t] = ((const f32x4*)node)[j * 256 + t];
  if (t == 0) {
    out2[m] = adj[p];
    out2[16352 + m] = (float)i;
    out2[2 * 16352 + m] = (float)j;
  }
}

// ---------------- host ----------------
extern "C" void kernel_launch(void* const* d_in, const int* in_sizes, int n_in,
                              void* d_out, int out_size, void* d_ws, size_t ws_size,
                              hipStream_t stream) {
  const float* node_in = (const float*)d_in[1];
  const float* coords  = (const float*)d_in[2];
  const void*  imh     = d_in[3];
  const void*  imw     = d_in[4];
  const float* sp_w1 = (const float*)d_in[5];
  const float* sp_b1 = (const float*)d_in[6];
  const float* sp_w2 = (const float*)d_in[7];
  const float* sp_b2 = (const float*)d_in[8];
  const float* sp_w3 = (const float*)d_in[9];
  const float* sp_b3 = (const float*)d_in[10];
  const float* att_w1 = (const float*)d_in[11];
  const float* att_b1 = (const float*)d_in[12];
  const float* att_w2 = (const float*)d_in[13];
  const float* att_b2 = (const float*)d_in[14];
  const float* att_w3 = (const float*)d_in[15];
  const float* att_b3 = (const float*)d_in[16];
  const float* adj_w  = (const float*)d_in[17];
  const float* adj_b  = (const float*)d_in[18];
  const float* lnh_g  = (const float*)d_in[19];
  const float* lnh_b  = (const float*)d_in[20];
  const float* lno_g  = (const float*)d_in[21];
  const float* lno_b  = (const float*)d_in[22];

  char* w = (char*)d_ws;
  size_t off = 0;
  auto alloc = [&](size_t bytes) -> char* {
    char* p = w + off;
    off += (bytes + 255) & ~(size_t)255;
    return p;
  };
  __bf16* W1at  = (__bf16*)alloc((size_t)1024 * 1024 * 2);
  __bf16* W1bt  = (__bf16*)alloc((size_t)1024 * 1024 * 2);
  __bf16* W2t   = (__bf16*)alloc((size_t)1024 * 1024 * 2);
  __bf16* W3t   = (__bf16*)alloc((size_t)1024 * 1024 * 2);
  __bf16* SpW1t = (__bf16*)alloc(128 * 64 * 2);
  __bf16* SpW2t = (__bf16*)alloc(256 * 128 * 2);
  __bf16* SpW3t = (__bf16*)alloc(1024 * 256 * 2);
  float*  b3s   = (float*)alloc(1024 * 4);
  __bf16* f36   = (__bf16*)alloc((size_t)16384 * 64 * 2);
  __bf16* sp1   = (__bf16*)alloc((size_t)16384 * 128 * 2);
  __bf16* sp2   = (__bf16*)alloc((size_t)16384 * 256 * 2);
  __bf16* spb   = (__bf16*)alloc((size_t)16384 * 1024 * 2);
  __bf16* u2    = (__bf16*)alloc((size_t)16384 * 1024 * 2);
  float*  H1    = (float*)alloc((size_t)32 * 1024 * 4);
  float*  N1    = (float*)alloc((size_t)512 * 1024 * 4);
  float*  adjpre = (float*)alloc(16384 * 4);
  float*  adj    = (float*)alloc(16384 * 4);
  float*  node_f = (float*)alloc((size_t)512 * 1024 * 4);
  float*  hn_f   = (float*)alloc((size_t)32 * 1024 * 4);
  __bf16* node_b = (__bf16*)alloc((size_t)512 * 1024 * 2);
  __bf16* hn_b   = (__bf16*)alloc((size_t)32 * 1024 * 2);
  float*  hn_msgb = (float*)alloc((size_t)32 * 1024 * 4);
  float*  nd_msgb = (float*)alloc((size_t)512 * 1024 * 4);
  if (off > ws_size) return;  // fail loud (outputs stay poisoned) rather than corrupt

  prep_att<<<4096, 256, 0, stream>>>(att_w1, att_w2, att_w3, att_b3, W1at, W1bt, W2t, W3t, b3s);
  prep_sp<<<1024, 256, 0, stream>>>(sp_w1, sp_w2, sp_w3, SpW1t, SpW2t, SpW3t);
  init_nodes<<<2048, 256, 0, stream>>>(node_in, node_f, node_b, hn_f, hn_b);
  spatial_k<<<64, 256, 0, stream>>>(coords, imh, imw, f36);

  gemm_bt<0><<<dim3(128, 1), 256, 0, stream>>>(f36, SpW1t, sp_b1, sp1, 16384, 128, 64);
  gemm_bt<0><<<dim3(128, 2), 256, 0, stream>>>(sp1, SpW2t, sp_b2, sp2, 16384, 256, 128);
  gemm_bt<0><<<dim3(128, 8), 256, 0, stream>>>(sp2, SpW3t, sp_b3, spb, 16384, 1024, 256);
  gemm_bt<1><<<dim3(128, 8), 256, 0, stream>>>(spb, W2t, att_b2, u2, 16384, 1024, 1024);

  for (int iter = 0; iter < 2; ++iter) {
    gemm_bt<2><<<dim3(1, 8), 256, 0, stream>>>(hn_b, W1at, att_b1, H1, 32, 1024, 1024);
    gemm_bt<3><<<dim3(4, 8), 256, 0, stream>>>(node_b, W1bt, nullptr, N1, 512, 1024, 1024);
    hipMemsetAsync(adjpre, 0, 16384 * 4, stream);
    fused_out<<<dim3(128, 8), 256, 0, stream>>>(u2, H1, N1, W3t, b3s, adj_w, adjpre);
    adj_fin<<<64, 256, 0, stream>>>(adjpre, adj_b, adj);
    hn_msg_k<<<32, 256, 0, stream>>>(adj, node_f, hn_msgb);
    nd_msg_k<<<512, 256, 0, stream>>>(adj, hn_f, nd_msgb);
    ln_k<<<512, 256, 0, stream>>>(node_f, nd_msgb, lno_g, lno_b, node_b);
    ln_k<<<32, 256, 0, stream>>>(hn_f, hn_msgb, lnh_g, lnh_b, hn_b);
  }

  gather_k<<<16384, 256, 0, stream>>>(hn_f, node_f, adj, (float*)d_out);
}

// Round 2
// 525.626 us; speedup vs baseline: 1.1422x; 1.1422x over previous
//
#include <hip/hip_runtime.h>
#include <hip/hip_bf16.h>

// GCN_55602646614506 — round 2.
// Changes vs r1: (1) all GEMM staging via __builtin_amdgcn_global_load_lds (m97
// structure, linear LDS, 2-phase); (2) hdn precomputed once per iter (was rebuilt
// 8x inside fused GEMM); (3) LDS-tiled coalesced weight transposes (prep was ~70us
// of strided reads); (4) H1+N1 one kernel, 32x128 tiles, 136 blocks; (5) msg/ln/adj_fin
// fused; (6) FIX missing __syncthreads in ln_k variance reduction (r1 raced, passed by luck).

typedef __attribute__((ext_vector_type(4))) float  f32x4;
typedef __attribute__((ext_vector_type(8))) __bf16 bf16x8;
typedef __attribute__((ext_vector_type(4))) __bf16 bf16x4;

#define FEPS 1e-10f
#define LNEPS 1e-5f
#define GAMA_F 0.9f

__device__ __forceinline__ void gload16(const void* g, void* l) {
  __builtin_amdgcn_global_load_lds(
      (const __attribute__((address_space(1))) void*)g,
      (__attribute__((address_space(3))) void*)l, 16, 0, 0);
}

// ---------------- weight prep: LDS-tiled transposes ----------------
// grid 832 blocks x 256 threads
__global__ void prep_all(const float* __restrict__ w1, const float* __restrict__ w2,
                         const float* __restrict__ w3, const float* __restrict__ spw3,
                         __bf16* __restrict__ W1at, __bf16* __restrict__ W1bt,
                         __bf16* __restrict__ W2t, __bf16* __restrict__ W3t,
                         __bf16* __restrict__ SpW3t) {
  __shared__ float tile[64][65];
  const int b = blockIdx.x, t = threadIdx.x;
  const int tc = t & 63, tr = t >> 6;           // tc fastest (coalesce), tr = 4-row group
  if (b < 256) {
    // w1 (16, 2048, 64) -> W1at[ck][d] (d<1024), W1bt[ck][d] (d>=1024)
    const int c = b >> 4, d0 = (b & 15) << 6;
    #pragma unroll
    for (int pass = 0; pass < 2; ++pass) {
      const float* src = w1 + (size_t)c * 131072 + (size_t)(d0 + pass * 1024) * 64;
      __bf16* dst = pass ? W1bt : W1at;
      if (pass) __syncthreads();
      #pragma unroll
      for (int q = 0; q < 16; ++q) {
        int dd = q * 4 + tr;
        tile[dd][tc] = src[dd * 64 + tc];       // read row dd, k=tc coalesced
      }
      __syncthreads();
      #pragma unroll
      for (int q = 0; q < 16; ++q) {
        int kk = q * 4 + tr;
        dst[(size_t)(c * 64 + kk) * 1024 + d0 + tc] = (__bf16)tile[tc][kk];
      }
    }
  } else if (b < 512) {
    // w2 (16, 1024, 64) -> W2t[ck][s]
    const int bb = b - 256, c = bb >> 4, s0 = (bb & 15) << 6;
    const float* src = w2 + (size_t)c * 65536 + (size_t)s0 * 64;
    #pragma unroll
    for (int q = 0; q < 16; ++q) {
      int ss = q * 4 + tr;
      tile[ss][tc] = src[ss * 64 + tc];
    }
    __syncthreads();
    #pragma unroll
    for (int q = 0; q < 16; ++q) {
      int kk = q * 4 + tr;
      W2t[(size_t)(c * 64 + kk) * 1024 + s0 + tc] = (__bf16)tile[tc][kk];
    }
  } else if (b < 768) {
    // w3 (16, 64, 1024) -> W3t[o][ck]
    const int bb = b - 512, c = bb >> 4, o0 = (bb & 15) << 6;
    const float* src = w3 + (size_t)c * 65536;
    #pragma unroll
    for (int q = 0; q < 16; ++q) {
      int kk = q * 4 + tr;
      tile[kk][tc] = src[kk * 1024 + o0 + tc];  // o=tc coalesced
    }
    __syncthreads();
    #pragma unroll
    for (int q = 0; q < 16; ++q) {
      int oo = q * 4 + tr;
      W3t[(size_t)(o0 + oo) * 1024 + c * 64 + tc] = (__bf16)tile[tc][oo];
    }
  } else {
    // sp_w3 (256, 1024) -> SpW3t[o][k]
    const int bb = b - 768, o0 = (bb >> 2) << 6, k0 = (bb & 3) << 6;
    #pragma unroll
    for (int q = 0; q < 16; ++q) {
      int kk = q * 4 + tr;
      tile[kk][tc] = spw3[(size_t)(k0 + kk) * 1024 + o0 + tc];
    }
    __syncthreads();
    #pragma unroll
    for (int q = 0; q < 16; ++q) {
      int oo = q * 4 + tr;
      SpW3t[(size_t)(o0 + oo) * 256 + k0 + tc] = (__bf16)tile[tc][oo];
    }
  }
}

// small weights + b3 sum; grid 128 x 256
__global__ void prep_sp2(const float* __restrict__ w1, const float* __restrict__ w2,
                         const float* __restrict__ b3,
                         __bf16* __restrict__ W1t, __bf16* __restrict__ W2t,
                         float* __restrict__ b3s) {
  int gid = blockIdx.x * 256 + threadIdx.x;     // 0..32767
  if (gid < 8192) {                             // SpW1t[n][k], K padded 36->64
    int n = gid >> 6, k = gid & 63;
    W1t[gid] = (k < 36) ? (__bf16)w1[k * 128 + n] : (__bf16)0.f;
  }
  {                                             // SpW2t[n][k] (256x128)
    int n = gid >> 7, k = gid & 127;
    W2t[gid] = (__bf16)w2[k * 256 + n];
  }
  if (gid < 1024) {
    float s = 0.f;
    for (int cc = 0; cc < 16; ++cc) s += b3[cc * 1024 + gid];
    b3s[gid] = s;
  }
}

__global__ void init_nodes(const float* __restrict__ node_in, float* __restrict__ node_f,
                           __bf16* __restrict__ node_b, float* __restrict__ hn_f,
                           __bf16* __restrict__ hn_b) {
  int gid = blockIdx.x * 256 + threadIdx.x;     // 0..524287
  float v = node_in[gid];
  node_f[gid] = v;
  node_b[gid] = (__bf16)v;
  if (gid < 32 * 1024) { hn_f[gid] = v; hn_b[gid] = (__bf16)v; }
}

// ---------------- spatial features ----------------
__device__ __forceinline__ float read_dim(const void* p) {
  int iv = *(const int*)p;
  if (iv > 0 && iv < (1 << 20)) return (float)iv;
  return *(const float*)p;
}

__global__ void spatial_k(const float* __restrict__ coords, const void* __restrict__ imh,
                          const void* __restrict__ imw, __bf16* __restrict__ f36) {
  int p = blockIdx.x * 256 + threadIdx.x;       // 0..16383
  int i = p >> 9, j = p & 511;
  float H = read_dim(imh), W = read_dim(imw);
  f32x4 b1 = ((const f32x4*)coords)[i];
  f32x4 b2 = ((const f32x4*)coords)[j];
  float c1x = (b1[0] + b1[2]) * 0.5f, c1y = (b1[1] + b1[3]) * 0.5f;
  float c2x = (b2[0] + b2[2]) * 0.5f, c2y = (b2[1] + b2[3]) * 0.5f;
  float b1w = b1[2] - b1[0], b1h = b1[3] - b1[1];
  float b2w = b2[2] - b2[0], b2h = b2[3] - b2[1];
  float dx = fabsf(c2x - c1x) / (b1w + FEPS);
  float dy = fabsf(c2y - c1y) / (b1h + FEPS);
  float ltx = fmaxf(b1[0], b2[0]), lty = fmaxf(b1[1], b2[1]);
  float rbx = fminf(b1[2], b2[2]), rby = fminf(b1[3], b2[3]);
  float inter = fmaxf(rbx - ltx, 0.f) * fmaxf(rby - lty, 0.f);
  float a1 = b1w * b1h, a2 = b2w * b2h;
  float iou = inter / (a1 + a2 - inter);
  float f[18];
  f[0] = c1x / W;  f[1] = c1y / H;  f[2] = c2x / W;  f[3] = c2y / H;
  f[4] = b1w / W;  f[5] = b1h / H;  f[6] = b2w / W;  f[7] = b2h / H;
  f[8] = a1 / (H * W); f[9] = a2 / (H * W); f[10] = a2 / (a1 + FEPS);
  f[11] = b1w / (b1h + FEPS); f[12] = b2w / (b2h + FEPS); f[13] = iou;
  f[14] = (c2x > c1x) ? dx : 0.f; f[15] = (c2x < c1x) ? dx : 0.f;
  f[16] = (c2y > c1y) ? dy : 0.f; f[17] = (c2y < c1y) ? dy : 0.f;
  __bf16 o[64];
  #pragma unroll
  for (int q = 0; q < 18; ++q) { o[q] = (__bf16)f[q]; o[18 + q] = (__bf16)logf(f[q] + FEPS); }
  #pragma unroll
  for (int q = 36; q < 64; ++q) o[q] = (__bf16)0.f;
  bf16x8* dst = (bf16x8*)(f36 + (size_t)p * 64);
  #pragma unroll
  for (int q = 0; q < 8; ++q) dst[q] = *(bf16x8*)&o[q * 8];
}

// ---------------- MFMA GEMM, m97 structure: global_load_lds + linear LDS ----------------
// EPI: 0 relu+bias->bf16; 1 bias->bf16; 2 bias->f32; 3 plain->f32; 4 adjacency-dot epilogue
template <int EPI>
__global__ __launch_bounds__(256)
void gemm_bt(const __bf16* __restrict__ A, const __bf16* __restrict__ Bt,
             const float* __restrict__ bias, void* __restrict__ C,
             int M, int N, int K,
             const float* __restrict__ adjw = nullptr,
             float* __restrict__ adjpre = nullptr) {
  __shared__ __align__(16) __bf16 As[128 * 64];
  __shared__ __align__(16) __bf16 Bs[128 * 64];
  const int t = threadIdx.x;
  const int lane = t & 63, wv = t >> 6;
  const int wr = wv >> 1, wc = wv & 1;
  const int lr = lane & 15, lg = lane >> 4;
  const int lrow = lane >> 3, lcol = (lane & 7) << 3;
  const int m0 = blockIdx.x * 128, n0 = blockIdx.y * 128;

  f32x4 acc[4][4] = {};
  const int nkt = K >> 6;
  for (int kt = 0; kt < nkt; ++kt) {
    const int k0 = kt << 6;
    #pragma unroll
    for (int it = 0; it < 4; ++it) {
      const int rbase = wv * 32 + it * 8;
      gload16(A + (size_t)(m0 + rbase + lrow) * K + k0 + lcol, &As[rbase * 64]);
      gload16(Bt + (size_t)(n0 + rbase + lrow) * K + k0 + lcol, &Bs[rbase * 64]);
    }
    __syncthreads();                            // drains vmcnt (compiler-inserted)
    #pragma unroll
    for (int ks = 0; ks < 2; ++ks) {
      bf16x8 af[4], bfr[4];
      #pragma unroll
      for (int mi = 0; mi < 4; ++mi)
        af[mi] = *(const bf16x8*)&As[(wr * 64 + mi * 16 + lr) * 64 + ks * 32 + lg * 8];
      #pragma unroll
      for (int ni = 0; ni < 4; ++ni)
        bfr[ni] = *(const bf16x8*)&Bs[(wc * 64 + ni * 16 + lr) * 64 + ks * 32 + lg * 8];
      #pragma unroll
      for (int mi = 0; mi < 4; ++mi)
        #pragma unroll
        for (int ni = 0; ni < 4; ++ni)
          acc[mi][ni] = __builtin_amdgcn_mfma_f32_16x16x32_bf16(af[mi], bfr[ni], acc[mi][ni], 0, 0, 0);
    }
    __syncthreads();
  }

  if constexpr (EPI == 4) {
    float b3v[4], awv[4];
    #pragma unroll
    for (int ni = 0; ni < 4; ++ni) {
      int Cc = n0 + wc * 64 + ni * 16 + lr;
      b3v[ni] = bias[Cc];
      awv[ni] = adjw[Cc];
    }
    #pragma unroll
    for (int mi = 0; mi < 4; ++mi) {
      #pragma unroll
      for (int r = 0; r < 4; ++r) {
        float s = 0.f;
        #pragma unroll
        for (int ni = 0; ni < 4; ++ni)
          s += fmaxf(acc[mi][ni][r] + b3v[ni], 0.f) * awv[ni];
        s += __shfl_xor(s, 1);
        s += __shfl_xor(s, 2);
        s += __shfl_xor(s, 4);
        s += __shfl_xor(s, 8);
        if (lr == 0)
          atomicAdd(&adjpre[m0 + wr * 64 + mi * 16 + lg * 4 + r], s);
      }
    }
  } else {
    #pragma unroll
    for (int mi = 0; mi < 4; ++mi) {
      #pragma unroll
      for (int r = 0; r < 4; ++r) {
        int R = m0 + wr * 64 + mi * 16 + lg * 4 + r;
        #pragma unroll
        for (int ni = 0; ni < 4; ++ni) {
          int Cc = n0 + wc * 64 + ni * 16 + lr;
          float v = acc[mi][ni][r];
          if constexpr (EPI == 0) {
            ((__bf16*)C)[(size_t)R * N + Cc] = (__bf16)fmaxf(v + bias[Cc], 0.f);
          } else if constexpr (EPI == 1) {
            ((__bf16*)C)[(size_t)R * N + Cc] = (__bf16)(v + bias[Cc]);
          } else if constexpr (EPI == 2) {
            ((float*)C)[(size_t)R * N + Cc] = v + bias[Cc];
          } else {
            ((float*)C)[(size_t)R * N + Cc] = v;
          }
        }
      }
    }
  }
}

// ---------------- H1 + N1 in one launch: 32x128 tiles, grid (17, 8) ----------------
__global__ __launch_bounds__(256)
void gemm_u1(const __bf16* __restrict__ hn_b, const __bf16* __restrict__ node_b,
             const __bf16* __restrict__ W1at, const __bf16* __restrict__ W1bt,
             const float* __restrict__ b1, float* __restrict__ H1, float* __restrict__ N1) {
  __shared__ __align__(16) __bf16 As[32 * 64];
  __shared__ __align__(16) __bf16 Bs[128 * 64];
  const int t = threadIdx.x;
  const int lane = t & 63, wv = t >> 6;
  const int wr = wv >> 1, wc = wv & 1;
  const int lr = lane & 15, lg = lane >> 4;
  const int lrow = lane >> 3, lcol = (lane & 7) << 3;
  const bool isH = (blockIdx.x == 0);
  const __bf16* Ap = isH ? hn_b : node_b + (size_t)(blockIdx.x - 1) * 32 * 1024;
  const __bf16* Bp = isH ? W1at : W1bt;
  const int n0 = blockIdx.y * 128;

  f32x4 acc[4] = {};
  for (int kt = 0; kt < 16; ++kt) {
    const int k0 = kt << 6;
    gload16(Ap + (size_t)(wv * 8 + lrow) * 1024 + k0 + lcol, &As[(wv * 8) * 64]);
    #pragma unroll
    for (int it = 0; it < 4; ++it) {
      const int rbase = wv * 32 + it * 8;
      gload16(Bp + (size_t)(n0 + rbase + lrow) * 1024 + k0 + lcol, &Bs[rbase * 64]);
    }
    __syncthreads();
    #pragma unroll
    for (int ks = 0; ks < 2; ++ks) {
      bf16x8 af = *(const bf16x8*)&As[(wr * 16 + lr) * 64 + ks * 32 + lg * 8];
      #pragma unroll
      for (int ni = 0; ni < 4; ++ni) {
        bf16x8 bfr = *(const bf16x8*)&Bs[(wc * 64 + ni * 16 + lr) * 64 + ks * 32 + lg * 8];
        acc[ni] = __builtin_amdgcn_mfma_f32_16x16x32_bf16(af, bfr, acc[ni], 0, 0, 0);
      }
    }
    __syncthreads();
  }
  #pragma unroll
  for (int ni = 0; ni < 4; ++ni) {
    #pragma unroll
    for (int r = 0; r < 4; ++r) {
      int R = wr * 16 + lg * 4 + r;
      int Cc = n0 + wc * 64 + ni * 16 + lr;
      float v = acc[ni][r];
      if (isH) H1[(size_t)R * 1024 + Cc] = v + b1[Cc];
      else     N1[((size_t)(blockIdx.x - 1) * 32 + R) * 1024 + Cc] = v;
    }
  }
}

// ---------------- hdn = relu((H1[i]+N1[j]) * u2), once per iteration ----------------
__global__ void build_hdn(const __bf16* __restrict__ u2, const float* __restrict__ H1,
                          const float* __restrict__ N1, __bf16* __restrict__ hdn) {
  int gid = blockIdx.x * 256 + threadIdx.x;     // 2M threads, 8 elems each
  int p = gid >> 7, c8 = (gid & 127) << 3;
  int i = p >> 9, j = p & 511;
  bf16x8 u = *(const bf16x8*)(u2 + (size_t)p * 1024 + c8);
  const float* hp = H1 + (size_t)i * 1024 + c8;
  const float* np = N1 + (size_t)j * 1024 + c8;
  f32x4 h0 = *(const f32x4*)hp, h1 = *(const f32x4*)(hp + 4);
  f32x4 n0 = *(const f32x4*)np, n1 = *(const f32x4*)(np + 4);
  bf16x8 o;
  #pragma unroll
  for (int e = 0; e < 4; ++e) {
    o[e]     = (__bf16)fmaxf((h0[e] + n0[e]) * (float)u[e], 0.f);
    o[4 + e] = (__bf16)fmaxf((h1[e] + n1[e]) * (float)u[4 + e], 0.f);
  }
  *(bf16x8*)(hdn + (size_t)p * 1024 + c8) = o;
}

// ---------------- messages (both directions, adj computed on the fly) ----------------
__global__ void msg_k(const float* __restrict__ adjpre, const float* __restrict__ adjb,
                      const float* __restrict__ node, const float* __restrict__ hn,
                      float* __restrict__ hn_msg, float* __restrict__ nd_msg) {
  int row = blockIdx.x, t = threadIdx.x;
  float ab = adjb[0];
  if (row < 32) {
    f32x4 acc = {0.f, 0.f, 0.f, 0.f};
    for (int j = 0; j < 512; ++j)
      acc += fmaxf(adjpre[row * 512 + j] + ab, 0.f) * ((const f32x4*)node)[j * 256 + t];
    ((f32x4*)hn_msg)[row * 256 + t] = acc;
  } else {
    int j = row - 32;
    f32x4 acc = {0.f, 0.f, 0.f, 0.f};
    for (int i = 0; i < 32; ++i)
      acc += fmaxf(adjpre[i * 512 + j] + ab, 0.f) * ((const f32x4*)hn)[i * 256 + t];
    ((f32x4*)nd_msg)[j * 256 + t] = acc;
  }
}

// ---------------- LayerNorm (node rows 0..511, human rows 512..543) ----------------
__global__ void ln_k(float* __restrict__ node_f, float* __restrict__ hn_f,
                     const float* __restrict__ nd_msg, const float* __restrict__ hn_msg,
                     const float* __restrict__ lno_g, const float* __restrict__ lno_b,
                     const float* __restrict__ lnh_g, const float* __restrict__ lnh_b,
                     __bf16* __restrict__ node_bb, __bf16* __restrict__ hn_bb) {
  __shared__ float sbuf[4];
  int row = blockIdx.x, t = threadIdx.x;
  bool isN = row < 512;
  int r = isN ? row : row - 512;
  float* X = (isN ? node_f : hn_f) + (size_t)r * 1024;
  const float* Mg = (isN ? nd_msg : hn_msg) + (size_t)r * 1024;
  const float* g = isN ? lno_g : lnh_g;
  const float* bb = isN ? lno_b : lnh_b;
  __bf16* Xb = (isN ? node_bb : hn_bb) + (size_t)r * 1024;

  f32x4 x = ((const f32x4*)X)[t];
  f32x4 m = ((const f32x4*)Mg)[t];
  f32x4 y;
  #pragma unroll
  for (int e = 0; e < 4; ++e) y[e] = x[e] * GAMA_F + (1.0f - GAMA_F) * m[e];
  float s = y[0] + y[1] + y[2] + y[3];
  #pragma unroll
  for (int mm = 32; mm >= 1; mm >>= 1) s += __shfl_xor(s, mm);
  if ((t & 63) == 0) sbuf[t >> 6] = s;
  __syncthreads();
  float mean = (sbuf[0] + sbuf[1] + sbuf[2] + sbuf[3]) * (1.0f / 1024.0f);
  __syncthreads();
  f32x4 d;
  #pragma unroll
  for (int e = 0; e < 4; ++e) d[e] = y[e] - mean;
  float sq = d[0] * d[0] + d[1] * d[1] + d[2] * d[2] + d[3] * d[3];
  #pragma unroll
  for (int mm = 32; mm >= 1; mm >>= 1) sq += __shfl_xor(sq, mm);
  if ((t & 63) == 0) sbuf[t >> 6] = sq;
  __syncthreads();                              // r1 was missing this — raced
  float var = (sbuf[0] + sbuf[1] + sbuf[2] + sbuf[3]) * (1.0f / 1024.0f);
  float inv = rsqrtf(var + LNEPS);
  f32x4 gg = ((const f32x4*)g)[t];
  f32x4 bv = ((const f32x4*)bb)[t];
  f32x4 o;
  bf16x4 ob;
  #pragma unroll
  for (int e = 0; e < 4; ++e) { o[e] = d[e] * inv * gg[e] + bv[e]; ob[e] = (__bf16)o[e]; }
  ((f32x4*)X)[t] = o;
  *(bf16x4*)(Xb + t * 4) = ob;
}

// ---------------- gather (adj finalized on the fly) ----------------
__global__ void gather_k(const float* __restrict__ hn, const float* __restrict__ node,
                         const float* __restrict__ adjpre, const float* __restrict__ adjb,
                         float* __restrict__ out) {
  int p = blockIdx.x, t = threadIdx.x;
  int i = p >> 9, j = p & 511;
  if (i == j) return;
  int m = p - (p + 512) / 513;                  // skip diagonal pairs (p = 513*i)
  float* out0 = out;
  float* out1 = out + (size_t)16352 * 1024;
  float* out2 = out1 + (size_t)16352 * 1024;
  ((f32x4*)out0)[(size_t)m * 256 + t] = ((const f32x4*)hn)[i * 256 + t];
  ((f32x4*)out1)[(size_t)m * 256 + t] = ((const f32x4*)node)[j * 256 + t];
  if (t == 0) {
    out2[m] = fmaxf(adjpre[p] + adjb[0], 0.f);
    out2[16352 + m] = (float)i;
    out2[2 * 16352 + m] = (float)j;
  }
}

// ---------------- host ----------------
extern "C" void kernel_launch(void* const* d_in, const int* in_sizes, int n_in,
                              void* d_out, int out_size, void* d_ws, size_t ws_size,
                              hipStream_t stream) {
  const float* node_in = (const float*)d_in[1];
  const float* coords  = (const float*)d_in[2];
  const void*  imh     = d_in[3];
  const void*  imw     = d_in[4];
  const float* sp_w1 = (const float*)d_in[5];
  const float* sp_b1 = (const float*)d_in[6];
  const float* sp_w2 = (const float*)d_in[7];
  const float* sp_b2 = (const float*)d_in[8];
  const float* sp_w3 = (const float*)d_in[9];
  const float* sp_b3 = (const float*)d_in[10];
  const float* att_w1 = (const float*)d_in[11];
  const float* att_b1 = (const float*)d_in[12];
  const float* att_w2 = (const float*)d_in[13];
  const float* att_b2 = (const float*)d_in[14];
  const float* att_w3 = (const float*)d_in[15];
  const float* att_b3 = (const float*)d_in[16];
  const float* adj_w  = (const float*)d_in[17];
  const float* adj_b  = (const float*)d_in[18];
  const float* lnh_g  = (const float*)d_in[19];
  const float* lnh_b  = (const float*)d_in[20];
  const float* lno_g  = (const float*)d_in[21];
  const float* lno_b  = (const float*)d_in[22];

  char* w = (char*)d_ws;
  size_t off = 0;
  auto alloc = [&](size_t bytes) -> char* {
    char* p = w + off;
    off += (bytes + 255) & ~(size_t)255;
    return p;
  };
  __bf16* W1at  = (__bf16*)alloc((size_t)1024 * 1024 * 2);
  __bf16* W1bt  = (__bf16*)alloc((size_t)1024 * 1024 * 2);
  __bf16* W2t   = (__bf16*)alloc((size_t)1024 * 1024 * 2);
  __bf16* W3t   = (__bf16*)alloc((size_t)1024 * 1024 * 2);
  __bf16* SpW1t = (__bf16*)alloc(128 * 64 * 2);
  __bf16* SpW2t = (__bf16*)alloc(256 * 128 * 2);
  __bf16* SpW3t = (__bf16*)alloc(1024 * 256 * 2);
  float*  b3s   = (float*)alloc(1024 * 4);
  __bf16* f36   = (__bf16*)alloc((size_t)16384 * 64 * 2);
  __bf16* sp1   = (__bf16*)alloc((size_t)16384 * 128 * 2);
  __bf16* sp2   = (__bf16*)alloc((size_t)16384 * 256 * 2);
  __bf16* spb   = (__bf16*)alloc((size_t)16384 * 1024 * 2);  // reused as hdn after u2
  __bf16* u2    = (__bf16*)alloc((size_t)16384 * 1024 * 2);
  float*  H1    = (float*)alloc((size_t)32 * 1024 * 4);
  float*  N1    = (float*)alloc((size_t)512 * 1024 * 4);
  float*  adjpre = (float*)alloc(16384 * 4);
  float*  node_f = (float*)alloc((size_t)512 * 1024 * 4);
  float*  hn_f   = (float*)alloc((size_t)32 * 1024 * 4);
  __bf16* node_b = (__bf16*)alloc((size_t)512 * 1024 * 2);
  __bf16* hn_b   = (__bf16*)alloc((size_t)32 * 1024 * 2);
  float*  hn_msgb = (float*)alloc((size_t)32 * 1024 * 4);
  float*  nd_msgb = (float*)alloc((size_t)512 * 1024 * 4);
  if (off > ws_size) return;  // fail loud (outputs stay poisoned) rather than corrupt

  prep_all<<<832, 256, 0, stream>>>(att_w1, att_w2, att_w3, sp_w3, W1at, W1bt, W2t, W3t, SpW3t);
  prep_sp2<<<128, 256, 0, stream>>>(sp_w1, sp_w2, att_b3, SpW1t, SpW2t, b3s);
  init_nodes<<<2048, 256, 0, stream>>>(node_in, node_f, node_b, hn_f, hn_b);
  spatial_k<<<64, 256, 0, stream>>>(coords, imh, imw, f36);

  gemm_bt<0><<<dim3(128, 1), 256, 0, stream>>>(f36, SpW1t, sp_b1, sp1, 16384, 128, 64);
  gemm_bt<0><<<dim3(128, 2), 256, 0, stream>>>(sp1, SpW2t, sp_b2, sp2, 16384, 256, 128);
  gemm_bt<0><<<dim3(128, 8), 256, 0, stream>>>(sp2, SpW3t, sp_b3, spb, 16384, 1024, 256);
  gemm_bt<1><<<dim3(128, 8), 256, 0, stream>>>(spb, W2t, att_b2, u2, 16384, 1024, 1024);

  __bf16* hdn = spb;  // spb dead after u2 — reuse 32MB
  for (int iter = 0; iter < 2; ++iter) {
    gemm_u1<<<dim3(17, 8), 256, 0, stream>>>(hn_b, node_b, W1at, W1bt, att_b1, H1, N1);
    build_hdn<<<8192, 256, 0, stream>>>(u2, H1, N1, hdn);
    hipMemsetAsync(adjpre, 0, 16384 * 4, stream);
    gemm_bt<4><<<dim3(128, 8), 256, 0, stream>>>(hdn, W3t, b3s, nullptr, 16384, 1024, 1024,
                                                 adj_w, adjpre);
    msg_k<<<544, 256, 0, stream>>>(adjpre, adj_b, node_f, hn_f, hn_msgb, nd_msgb);
    ln_k<<<544, 256, 0, stream>>>(node_f, hn_f, nd_msgb, hn_msgb,
                                  lno_g, lno_b, lnh_g, lnh_b, node_b, hn_b);
  }

  gather_k<<<16384, 256, 0, stream>>>(hn_f, node_f, adjpre, adj_b, (float*)d_out);
}